// Round 15
// baseline (1629.528 us; speedup 1.0000x reference)
//
#include <hip/hip_runtime.h>
#include <hip/hip_bf16.h>
#include <math.h>

typedef __attribute__((ext_vector_type(4))) float f32x4;
typedef __attribute__((ext_vector_type(8))) short bf16x8;
typedef __attribute__((ext_vector_type(4))) short bf16x4;

static __device__ __forceinline__ float bf2f(short u){
  unsigned int i = ((unsigned int)(unsigned short)u) << 16;
  return __builtin_bit_cast(float, i);
}
static __device__ __forceinline__ short f2bf(float f){
  unsigned int u = __builtin_bit_cast(unsigned int, f);
  u += 0x7FFFu + ((u >> 16) & 1u);   // RNE
  return (short)(u >> 16);
}

#define GLD16(g, l) __builtin_amdgcn_global_load_lds(                         \
    (const __attribute__((address_space(1))) void*)(g),                       \
    (__attribute__((address_space(3))) void*)(l), 16, 0, 0)

// ---------------------------------------------------------------------------
// gemm256 (round-8 proven best): 256x256 tile, BK=32, 8 waves (2m x 4n),
// per-wave 128x64. 4-slot LDS ring (128 KB), prefetch 3 tiles ahead via
// global_load_lds; drain-aware counted vmcnt (8/4/0) + raw s_barrier.
// T2 swizzle via pre-swizzled global source. T5 setprio.
// ---------------------------------------------------------------------------
template<typename CT, int SPLITS>
__global__ __launch_bounds__(512, 2) void gemm256(const short* __restrict__ A,
                                                  const short* __restrict__ BT,
                                                  CT* __restrict__ C,
                                                  float* __restrict__ P,
                                                  int M, int N, int K)
{
  extern __shared__ __align__(16) char smem[];   // 4 slots x (16KB A + 16KB B)
  const int tid = threadIdx.x;
  const int w = tid >> 6, lane = tid & 63;
  const int wm = w >> 2, wn = w & 3;
  const int g = lane >> 4, l16 = lane & 15;

  const int per_z = gridDim.x * gridDim.y;
  const int F = (blockIdx.z * gridDim.y + blockIdx.y) * gridDim.x + blockIdx.x;
  const int nwgF = per_z * gridDim.z;
  const int cpxF = nwgF >> 3;
  const int T = (F & 7) * cpxF + (F >> 3);
  const int zz = T / per_z, tt = T % per_z;
  const int m0 = (tt & 3) * 256;          // gridDim.x == 4 (M = 1024)
  const int n0 = (tt >> 2) * 256;

  const int Ks   = K / SPLITS;
  const int kbeg = zz * Ks;
  const int NT   = Ks >> 5;               // K-tiles of 32

  const int gg = (lane & 3) ^ ((lane >> 2) & 3) ^ ((lane >> 4) & 1);
  const short* aSrc[2]; const short* bSrc[2];
  int ldsOff[2];
  #pragma unroll
  for (int j = 0; j < 2; j++){
    int r = (w + j*8)*16 + (lane >> 2);
    aSrc[j] = A  + (size_t)(m0 + r) * K + kbeg + gg*8;
    bSrc[j] = BT + (size_t)(n0 + r) * K + kbeg + gg*8;
    ldsOff[j] = (w + j*8) * 1024;
  }

  const int sw = ((g ^ (l16 & 3) ^ ((l16 >> 2) & 1)) << 4);

  f32x4 acc[8][4];
  #pragma unroll
  for (int i = 0; i < 8; i++)
    #pragma unroll
    for (int j = 0; j < 4; j++) acc[i][j] = (f32x4){0.f,0.f,0.f,0.f};

  auto stage = [&](int b, int t){
    const int koff = t * 32;              // shorts
    char* dst = smem + b * 32768;
    #pragma unroll
    for (int j = 0; j < 2; j++){
      GLD16(aSrc[j] + koff, dst + ldsOff[j]);
      GLD16(bSrc[j] + koff, dst + 16384 + ldsOff[j]);
    }
  };

  auto wait_pub = [&](int ahead){       // ahead = # tiles staged beyond t
    if (ahead >= 3)      asm volatile("s_waitcnt vmcnt(8)" ::: "memory");
    else if (ahead == 2) asm volatile("s_waitcnt vmcnt(4)" ::: "memory");
    else                 asm volatile("s_waitcnt vmcnt(0)" ::: "memory");
    __builtin_amdgcn_s_barrier();
    asm volatile("" ::: "memory");
  };

  stage(0, 0);
  if (NT > 1) stage(1, 1);
  if (NT > 2) stage(2, 2);
  wait_pub(NT - 1 >= 2 ? (NT > 2 ? 3 : 2) : 1);

  const int arow = wm*128 + l16;          // + mi*16
  const int brow = wn*64  + l16;          // + ni*16

  for (int t = 0; t < NT; t++){
    const int sl = t & 3;
    if (t + 3 < NT) stage((t + 3) & 3, t + 3);

    const char* base = smem + sl * 32768;
    bf16x8 a[8], bb[4];
    #pragma unroll
    for (int mi = 0; mi < 8; mi++)
      a[mi] = *reinterpret_cast<const bf16x8*>(base + (arow + mi*16)*64 + sw);
    #pragma unroll
    for (int ni = 0; ni < 4; ni++)
      bb[ni] = *reinterpret_cast<const bf16x8*>(base + 16384 + (brow + ni*16)*64 + sw);

    __builtin_amdgcn_s_setprio(1);
    #pragma unroll
    for (int mi = 0; mi < 8; mi++)
      #pragma unroll
      for (int ni = 0; ni < 4; ni++)
        acc[mi][ni] = __builtin_amdgcn_mfma_f32_16x16x32_bf16(a[mi], bb[ni], acc[mi][ni], 0, 0, 0);
    __builtin_amdgcn_s_setprio(0);

    wait_pub(NT - 1 - t);
  }

  #pragma unroll
  for (int mi = 0; mi < 8; mi++){
    int row = m0 + wm*128 + mi*16 + g*4;
    #pragma unroll
    for (int ni = 0; ni < 4; ni++){
      int col = n0 + wn*64 + ni*16 + l16;
      #pragma unroll
      for (int r = 0; r < 4; r++){
        if constexpr (SPLITS > 1){
          P[(size_t)zz*M*N + (size_t)(row+r)*N + col] = acc[mi][ni][r];
        } else if constexpr (sizeof(CT) == 4){
          C[(size_t)(row+r)*N + col] = acc[mi][ni][r];
        } else {
          C[(size_t)(row+r)*N + col] = f2bf(acc[mi][ni][r]);
        }
      }
    }
  }
}

// ---------------------------------------------------------------------------
// Old 128x128 kernel (kept for the ragged-N down-projection, N=2112).
// ---------------------------------------------------------------------------
template<typename CT, int SPLITS>
__global__ __launch_bounds__(256) void gemm_bt(const short* __restrict__ A,
                                               const short* __restrict__ BT,
                                               CT* __restrict__ C,
                                               float* __restrict__ P,
                                               int M, int N, int K)
{
  __shared__ __align__(16) short As[2][128*32];
  __shared__ __align__(16) short Bs[2][128*32];
  const int tid = threadIdx.x;
  const int f   = blockIdx.y * 8 + blockIdx.x;
  const int nwg = 8 * gridDim.y;
  const int cpx = nwg >> 3;
  const int t   = (f & 7) * cpx + (f >> 3);
  const int m0  = (t & 7) * 128;
  const int n0  = (t >> 3) * 128;
  const int w = tid >> 6, lane = tid & 63;
  const int wr = w >> 1, wc = w & 1;
  const int g = lane >> 4, l16 = lane & 15;

  const int Ks   = K / SPLITS;
  const int kbeg = blockIdx.z * Ks;
  const int kend = kbeg + Ks;

  const int sr = lane >> 2;
  const int kc = (lane & 3) << 3;
  const int arow0 = m0 + w*16 + sr;
  const int arow1 = m0 + (w+4)*16 + sr;
  int brow0 = n0 + w*16 + sr;      if (brow0 >= N) brow0 = N - 1;
  int brow1 = n0 + (w+4)*16 + sr;  if (brow1 >= N) brow1 = N - 1;
  const short* aG0 = A  + (size_t)arow0 * K + kc;
  const short* aG1 = A  + (size_t)arow1 * K + kc;
  const short* bG0 = BT + (size_t)brow0 * K + kc;
  const short* bG1 = BT + (size_t)brow1 * K + kc;
  char* aL = (char*)As;
  char* bL = (char*)Bs;

  auto stage = [&](int buf, int k0){
    char* ab = aL + buf*8192;
    char* bb = bL + buf*8192;
    GLD16(aG0 + k0, ab + (w  )*1024);
    GLD16(aG1 + k0, ab + (w+4)*1024);
    GLD16(bG0 + k0, bb + (w  )*1024);
    GLD16(bG1 + k0, bb + (w+4)*1024);
  };

  f32x4 acc[4][4];
  #pragma unroll
  for (int i=0;i<4;i++)
    #pragma unroll
    for (int j=0;j<4;j++) acc[i][j] = (f32x4){0.f,0.f,0.f,0.f};

  stage(0, kbeg);
  __syncthreads();

  int cur = 0;
  for (int k0 = kbeg; k0 < kend; k0 += 32){
    if (k0 + 32 < kend) stage(cur ^ 1, k0 + 32);

    const char* ar = aL + cur*8192;
    const char* br = bL + cur*8192;
    bf16x8 af[4], bfm[4];
    #pragma unroll
    for (int mi=0;mi<4;mi++){
      int row = wr*64 + mi*16 + l16;
      af[mi] = *reinterpret_cast<const bf16x8*>(ar + row*64 + g*16);
    }
    #pragma unroll
    for (int ni=0;ni<4;ni++){
      int row = wc*64 + ni*16 + l16;
      bfm[ni] = *reinterpret_cast<const bf16x8*>(br + row*64 + g*16);
    }
    #pragma unroll
    for (int mi=0;mi<4;mi++)
      #pragma unroll
      for (int ni=0;ni<4;ni++)
        acc[mi][ni] = __builtin_amdgcn_mfma_f32_16x16x32_bf16(af[mi], bfm[ni], acc[mi][ni], 0, 0, 0);

    __syncthreads();
    cur ^= 1;
  }

  #pragma unroll
  for (int mi=0;mi<4;mi++){
    int row = m0 + wr*64 + mi*16 + g*4;
    #pragma unroll
    for (int ni=0;ni<4;ni++){
      int col = n0 + wc*64 + ni*16 + l16;
      if (col < N){
        #pragma unroll
        for (int r=0;r<4;r++){
          if constexpr (SPLITS > 1){
            P[(size_t)blockIdx.z*M*N + (size_t)(row+r)*N + col] = acc[mi][ni][r];
          } else if constexpr (sizeof(CT) == 4){
            C[(size_t)(row+r)*N + col] = acc[mi][ni][r];
          } else {
            C[(size_t)(row+r)*N + col] = f2bf(acc[mi][ni][r]);
          }
        }
      }
    }
  }
}

// ---------------------------------------------------------------------------
template<int NP>
__global__ __launch_bounds__(256) void reduceN(const float* __restrict__ p,
                                               float* __restrict__ out,
                                               int n4, int mn4)
{
  int i = blockIdx.x * 256 + threadIdx.x;
  const int stride = gridDim.x * 256;
  for (; i < n4; i += stride){
    f32x4 s = reinterpret_cast<const f32x4*>(p)[i];
    #pragma unroll
    for (int z = 1; z < NP; z++)
      s = s + reinterpret_cast<const f32x4*>(p)[(size_t)z*mn4 + i];
    reinterpret_cast<f32x4*>(out)[i] = s;
  }
}

// ---------------------------------------------------------------------------
__global__ __launch_bounds__(256) void transpose_f32_bf16(const float* __restrict__ src,
                                                          short* __restrict__ dst,
                                                          int R, int C)
{
  __shared__ float tl[64][68];
  const int tid = threadIdx.x;
  const int r0 = blockIdx.y * 64, c0 = blockIdx.x * 64;
  {
    const int lr = tid >> 4, lc = (tid & 15) << 2;
    #pragma unroll
    for (int p = 0; p < 4; p++){
      int row = p*16 + lr;
      f32x4 v = *reinterpret_cast<const f32x4*>(src + (size_t)(r0+row)*C + c0 + lc);
      *reinterpret_cast<f32x4*>(&tl[row][lc]) = v;
    }
  }
  __syncthreads();
  {
    const int n = tid >> 2, ks = (tid & 3) << 4;
    short tmp[16];
    #pragma unroll
    for (int j = 0; j < 16; j++) tmp[j] = f2bf(tl[ks + j][n]);
    short* d = dst + (size_t)(c0+n)*R + r0 + ks;
    *reinterpret_cast<bf16x8*>(d)     = *reinterpret_cast<bf16x8*>(&tmp[0]);
    *reinterpret_cast<bf16x8*>(d + 8) = *reinterpret_cast<bf16x8*>(&tmp[8]);
  }
}

// ---------------------------------------------------------------------------
__global__ __launch_bounds__(256) void conv_f32_bf16(const float* __restrict__ src,
                                                     short* __restrict__ dst, int n4)
{
  int i = blockIdx.x * 256 + threadIdx.x;
  const int stride = gridDim.x * 256;
  for (; i < n4; i += stride){
    f32x4 v = reinterpret_cast<const f32x4*>(src)[i];
    bf16x4 h; h[0]=f2bf(v[0]); h[1]=f2bf(v[1]); h[2]=f2bf(v[2]); h[3]=f2bf(v[3]);
    reinterpret_cast<bf16x4*>(dst)[i] = h;
  }
}

// ---------------------------------------------------------------------------
__device__ __forceinline__ void yarn_cs(int pos, int j, float& c, float& s){
  const double dim = 64.0;
  double pf = pow(10000.0, (2.0*(double)j)/dim);
  double inv_extra = 1.0/pf;
  double inv_inter = inv_extra/40.0;
  double lo = floor(dim*log(4096.0/(32.0*2.0*M_PI))/(2.0*log(10000.0)));
  double hi = ceil (dim*log(4096.0/(       2.0*M_PI))/(2.0*log(10000.0)));
  if (lo < 0.0) lo = 0.0;
  if (hi > dim - 1.0) hi = dim - 1.0;
  double denom = hi - lo; if (denom < 0.001) denom = 0.001;
  double ramp = ((double)j - lo)/denom;
  ramp = ramp < 0.0 ? 0.0 : (ramp > 1.0 ? 1.0 : ramp);
  double mask = 1.0 - ramp;
  float invf = (float)(inv_inter*(1.0 - mask) + inv_extra*mask);
  float ang = (float)pos * invf;
  c = cosf(ang); s = sinf(ang);
}

// ---------------------------------------------------------------------------
__global__ __launch_bounds__(256) void mla_rope_q(short* __restrict__ qb,
                                                  const int* __restrict__ positions)
{
  const int t = blockIdx.x;
  __shared__ float cs[32], sn[32];
  if (threadIdx.x < 32){
    float c, s; yarn_cs(positions[t], threadIdx.x, c, s);
    cs[threadIdx.x] = c; sn[threadIdx.x] = s;
  }
  __syncthreads();
  const float f = 0.004510548978043951f;   // 192^-0.5 * 256^-0.5
  short* row = qb + (size_t)t * 24576;
  for (int idx = threadIdx.x; idx < 128*160; idx += 256){
    int n = idx / 160, e = idx % 160;
    short* p = row + n*192;
    if (e < 128){
      p[e] = f2bf(bf2f(p[e]) * f);
    } else {
      int j = e - 128;
      float x1 = bf2f(p[128+j]), x2 = bf2f(p[160+j]);
      p[128+j] = f2bf((x1*cs[j] - x2*sn[j]) * f);
      p[160+j] = f2bf((x2*cs[j] + x1*sn[j]) * f);
    }
  }
}

// ---------------------------------------------------------------------------
// Fused post-down: q-rmsnorm (cols 0..1535 -> qAbf), kv-rmsnorm (1536..2047
// -> cbuf), k-rope (2048..2111 -> krope). One pass over downC.
// ---------------------------------------------------------------------------
__global__ __launch_bounds__(256) void mla_post(const float* __restrict__ dc,
                                                const float* __restrict__ qs,
                                                const float* __restrict__ kvs,
                                                const int* __restrict__ positions,
                                                short* __restrict__ qAbf,
                                                short* __restrict__ cbuf,
                                                short* __restrict__ krope)
{
  const int t = blockIdx.x;
  const float* row = dc + (size_t)t * 2112;
  float s1 = 0.f, s2 = 0.f;
  for (int i = threadIdx.x; i < 1536; i += 256){ float v = row[i]; s1 += v*v; }
  for (int i = threadIdx.x; i < 512;  i += 256){ float v = row[1536+i]; s2 += v*v; }
  #pragma unroll
  for (int off = 32; off >= 1; off >>= 1){ s1 += __shfl_xor(s1, off); s2 += __shfl_xor(s2, off); }
  __shared__ float red[8];
  if ((threadIdx.x & 63) == 0){ red[threadIdx.x >> 6] = s1; red[4 + (threadIdx.x >> 6)] = s2; }
  __syncthreads();
  s1 = red[0]+red[1]+red[2]+red[3];
  s2 = red[4]+red[5]+red[6]+red[7];
  const float rs1 = 1.0f / sqrtf(s1 / 1536.f + 1e-6f);
  const float rs2 = 1.0f / sqrtf(s2 / 512.f  + 1e-6f);
  for (int i = threadIdx.x; i < 1536; i += 256)
    qAbf[(size_t)t*1536 + i] = f2bf(row[i] * rs1 * qs[i]);
  for (int i = threadIdx.x; i < 512; i += 256)
    cbuf[(size_t)t*512 + i] = f2bf(row[1536+i] * rs2 * kvs[i]);
  if (threadIdx.x < 32){
    int j = threadIdx.x;
    float c, s; yarn_cs(positions[t], j, c, s);
    float x1 = row[2048 + j], x2 = row[2080 + j];
    krope[(size_t)t*64 + j]      = f2bf(x1*c - x2*s);
    krope[(size_t)t*64 + 32 + j] = f2bf(x2*c + x1*s);
  }
}

// ---------------------------------------------------------------------------
// Flash attention v3 (ROUND 15): 256 threads (4 waves x 16 q-rows = 64 rows),
// paired q-tiles (qt, 15-qt) -> uniform 17 iterations; 1024 blocks; 48 KB LDS
// -> 3 blocks/CU co-resident at ~140 VGPR (cross-block latency hiding).
// Same T14 prefetch + swizzles as the proven r13 kernel; NO launch-bounds cap.
// ---------------------------------------------------------------------------
__global__ void mla_attn3(const short* __restrict__ qb,
                          const short* __restrict__ kvup,
                          const short* __restrict__ krope,
                          short* __restrict__ attn_out)
{
  const int f = blockIdx.x;           // 0..1023
  const int xcd = f & 7, pos = f >> 3;      // pos 0..127
  const int n  = xcd*16 + (pos >> 3);       // head; 8 pair-blocks of a head same XCD
  const int pair = pos & 7;                 // 0..7
  const int tid = threadIdx.x, w = tid >> 6, lane = tid & 63;
  const int g = lane >> 4, l16 = lane & 15;

  __shared__ __align__(16) short Klds[64*192];    // 24 KB
  __shared__ __align__(16) short Vlds[128*64];    // 16 KB
  __shared__ __align__(16) short Plds[4][16*64];  // 8 KB
  char* KB = (char*)Klds; char* VB = (char*)Vlds; char* PB = (char*)Plds[w];

  bf16x8 kpre[6], vpre[4];

  int kS[6], kHB[6];
  #pragma unroll
  for (int c=0;c<6;c++){
    int lin = c*256 + tid;
    kS[c] = lin / 24; kHB[c] = (lin % 24) * 8;
  }
  int vS[4], vVB[4], vROT[4];
  #pragma unroll
  for (int c=0;c<4;c++){
    int lin = c*256 + tid;
    vS[c] = lin >> 4; vVB[c] = (lin & 15) << 3; vROT[c] = (lin & 15) & 7;
  }

  auto stage_load = [&](int S0){
    #pragma unroll
    for (int c=0;c<6;c++){
      const short* src = (kHB[c] < 128)
        ? kvup  + (size_t)(S0 + kS[c])*32768 + n*256 + kHB[c]
        : krope + (size_t)(S0 + kS[c])*64 + (kHB[c]-128);
      kpre[c] = *reinterpret_cast<const bf16x8*>(src);
    }
    #pragma unroll
    for (int c=0;c<4;c++)
      vpre[c] = *reinterpret_cast<const bf16x8*>(kvup + (size_t)(S0 + vS[c])*32768 + n*256 + 128 + vVB[c]);
  };
  auto stage_write = [&](){
    #pragma unroll
    for (int c=0;c<6;c++){
      unsigned byte = (unsigned)(kS[c]*384 + kHB[c]*2) ^ ((unsigned)(kS[c]&7)<<4);
      *reinterpret_cast<bf16x8*>(KB + byte) = kpre[c];
    }
    #pragma unroll
    for (int c=0;c<4;c++){
      #pragma unroll
      for (int i=0;i<8;i++){
        int v = vVB[c] + i;
        unsigned byte = (unsigned)(v*128 + ((vS[c]*2 + vROT[c]*16) & 127));
        *reinterpret_cast<short*>(VB + byte) = vpre[c][i];
      }
    }
  };

  stage_load(0);
  stage_write();
  __syncthreads();

  #pragma unroll
  for (int p = 0; p < 2; p++){
    const int qtl = p ? (15 - pair) : pair;   // 64-row tile index 0..15
    const int t0 = qtl * 64;
    const int last = qtl;                     // sb = 0..qtl

    bf16x8 qf[6];
    {
      const size_t qrow = (size_t)(t0 + w*16 + l16) * 24576 + (size_t)n * 192;
      #pragma unroll
      for (int c=0;c<6;c++)
        qf[c] = *reinterpret_cast<const bf16x8*>(qb + qrow + c*32 + g*8);
    }
    f32x4 o[8];
    #pragma unroll
    for (int i=0;i<8;i++) o[i] = (f32x4){0.f,0.f,0.f,0.f};
    float m[4], l[4];
    #pragma unroll
    for (int r=0;r<4;r++){ m[r] = -1e30f; l[r] = 0.f; }

    for (int sb = 0; sb <= last; sb++){
      const bool more = (sb < last) || (p == 0);
      if (more) stage_load((sb < last) ? (sb+1)*64 : 0);

      f32x4 S[4];
      __builtin_amdgcn_s_setprio(1);
      #pragma unroll
      for (int st=0; st<4; st++){
        f32x4 sacc = (f32x4){0.f,0.f,0.f,0.f};
        int srow = st*16 + l16;
        #pragma unroll
        for (int c=0;c<6;c++){
          unsigned byte = (unsigned)(srow*384 + c*64 + g*16) ^ ((unsigned)(srow&7)<<4);
          bf16x8 kf = *reinterpret_cast<const bf16x8*>(KB + byte);
          sacc = __builtin_amdgcn_mfma_f32_16x16x32_bf16(qf[c], kf, sacc, 0, 0, 0);
        }
        S[st] = sacc;
      }
      __builtin_amdgcn_s_setprio(0);

      if (sb == last && p >= 0){               // diagonal tile of this pass
        if (sb == qtl){
          #pragma unroll
          for (int st=0;st<4;st++){
            int sg = sb*64 + st*16 + l16;
            #pragma unroll
            for (int r=0;r<4;r++){
              int qg = t0 + w*16 + g*4 + r;
              if (sg > qg) S[st][r] = -1e30f;
            }
          }
        }
      }
      float alpha[4];
      #pragma unroll
      for (int r=0;r<4;r++){
        float mx = fmaxf(fmaxf(S[0][r],S[1][r]), fmaxf(S[2][r],S[3][r]));
        #pragma unroll
        for (int off=8; off>=1; off>>=1) mx = fmaxf(mx, __shfl_xor(mx, off));
        float mnew = fmaxf(m[r], mx);
        alpha[r] = __expf(m[r] - mnew);
        m[r] = mnew;
        l[r] *= alpha[r];
      }
      #pragma unroll
      for (int st=0;st<4;st++)
        #pragma unroll
        for (int r=0;r<4;r++)
          S[st][r] = __expf(S[st][r] - m[r]);
      #pragma unroll
      for (int r=0;r<4;r++){
        float sum = S[0][r]+S[1][r]+S[2][r]+S[3][r];
        #pragma unroll
        for (int off=8; off>=1; off>>=1) sum += __shfl_xor(sum, off);
        l[r] += sum;
      }
      #pragma unroll
      for (int vt=0; vt<8; vt++)
        #pragma unroll
        for (int r=0;r<4;r++) o[vt][r] *= alpha[r];

      #pragma unroll
      for (int st=0;st<4;st++){
        #pragma unroll
        for (int r=0;r<4;r++){
          int qrow = g*4 + r, scol = st*16 + l16;
          unsigned byte = (unsigned)(qrow*128 + scol*2) ^ ((unsigned)(qrow&7)<<4);
          *reinterpret_cast<short*>(PB + byte) = f2bf(S[st][r]);
        }
      }
      bf16x8 pf[2];
      #pragma unroll
      for (int c=0;c<2;c++){
        unsigned byte = (unsigned)(l16*128 + (c*32 + g*8)*2) ^ ((unsigned)(l16&7)<<4);
        pf[c] = *reinterpret_cast<const bf16x8*>(PB + byte);
      }
      __builtin_amdgcn_s_setprio(1);
      #pragma unroll
      for (int vt=0; vt<8; vt++){
        #pragma unroll
        for (int c=0;c<2;c++){
          int vrow = vt*16 + l16;
          int rot = (vrow >> 3) & 7;
          unsigned byte = (unsigned)(vrow*128 + ((c*64 + g*16 + rot*16) & 127));
          bf16x8 vf = *reinterpret_cast<const bf16x8*>(VB + byte);
          o[vt] = __builtin_amdgcn_mfma_f32_16x16x32_bf16(pf[c], vf, o[vt], 0, 0, 0);
        }
      }
      __builtin_amdgcn_s_setprio(0);

      if (more){
        __syncthreads();
        stage_write();
        __syncthreads();
      }
    }

    #pragma unroll
    for (int r=0;r<4;r++){
      float inv = 1.f / l[r];
      int t = t0 + w*16 + g*4 + r;
      #pragma unroll
      for (int vt=0;vt<8;vt++){
        int v = vt*16 + l16;
        attn_out[(size_t)t*16384 + n*128 + v] = f2bf(o[vt][r] * inv);
      }
    }
  }
}

// ---------------------------------------------------------------------------
extern "C" void kernel_launch(void* const* d_in, const int* in_sizes, int n_in,
                              void* d_out, int out_size, void* d_ws, size_t ws_size,
                              hipStream_t stream) {
  const float* x            = (const float*)d_in[0];
  const int*   positions    = (const int*)  d_in[1];
  const float* w_q_down     = (const float*)d_in[2];
  const float* q_norm_scale = (const float*)d_in[3];
  const float* w_q_up       = (const float*)d_in[4];
  const float* w_kv_down    = (const float*)d_in[5];
  const float* kv_norm_scale= (const float*)d_in[6];
  const float* w_kv_up      = (const float*)d_in[7];
  const float* w_o          = (const float*)d_in[8];

  char* p = (char*)d_ws;
  short* xbf   = (short*)p; p += (size_t)1024*7168*2;    // 14.7 MB
  short* wdT   = (short*)p; p += (size_t)2112*7168*2;    // 30.3 MB  [2112][7168]
  short* wquT  = (short*)p; p += (size_t)24576*1536*2;   // 75.5 MB
  short* wkuT  = (short*)p; p += (size_t)32768*512*2;    // 33.6 MB
  short* woT   = (short*)p; p += (size_t)7168*16384*2;   // 234.9 MB
  float* downC = (float*)p; p += (size_t)1024*2112*4;    // 8.7 MB
  short* qAbf  = (short*)p; p += (size_t)1024*1536*2;    // 3.1 MB
  short* q_b   = (short*)p; p += (size_t)1024*24576*2;   // 50.3 MB
  short* cbuf  = (short*)p; p += (size_t)1024*512*2;     // 1.0 MB
  short* krope = (short*)p; p += (size_t)1024*64*2;      // 0.13 MB
  short* kvup  = (short*)p; p += (size_t)1024*32768*2;   // 67 MB
  short* attn_o= (short*)p; p += (size_t)1024*16384*2;   // 33.6 MB

  float* pDown = (float*)q_b;     // 4 planes of 1024x2112 f32 (q_b dead here)
  float* pWo   = (float*)d_ws;    // 2 planes of 1024x7168 f32 (prepass bufs dead)

  hipFuncSetAttribute(reinterpret_cast<const void*>(&gemm256<short,1>),
                      hipFuncAttributeMaxDynamicSharedMemorySize, 131072);
  hipFuncSetAttribute(reinterpret_cast<const void*>(&gemm256<float,2>),
                      hipFuncAttributeMaxDynamicSharedMemorySize, 131072);

  dim3 blk(256);
  // ---- prepass: convert + transpose ----
  conv_f32_bf16<<<2048, blk, 0, stream>>>(x, xbf, 1024*7168/4);
  transpose_f32_bf16<<<dim3(24, 112),  blk, 0, stream>>>(w_q_down,  wdT,                     7168, 1536);
  transpose_f32_bf16<<<dim3(9, 112),   blk, 0, stream>>>(w_kv_down, wdT + (size_t)1536*7168, 7168, 576);
  transpose_f32_bf16<<<dim3(384, 24),  blk, 0, stream>>>(w_q_up,    wquT,                    1536, 24576);
  transpose_f32_bf16<<<dim3(512, 8),   blk, 0, stream>>>(w_kv_up,   wkuT,                    512,  32768);
  transpose_f32_bf16<<<dim3(112, 256), blk, 0, stream>>>(w_o,       woT,                     16384, 7168);

  // ---- fused down-proj (old kernel, split-K=4) + fused post ----
  gemm_bt<float, 4><<<dim3(8, 17, 4), blk, 0, stream>>>(xbf, wdT, (float*)nullptr, pDown, 1024, 2112, 7168);
  reduceN<4><<<1024, blk, 0, stream>>>(pDown, downC, 1024*2112/4, 1024*2112/4);
  mla_post<<<1024, blk, 0, stream>>>(downC, q_norm_scale, kv_norm_scale, positions, qAbf, cbuf, krope);

  // ---- up-projections (gemm256, round-8 config) ----
  gemm256<short, 1><<<dim3(4, 96), dim3(512), 131072, stream>>>(qAbf, wquT, q_b, nullptr, 1024, 24576, 1536);
  mla_rope_q<<<1024, blk, 0, stream>>>(q_b, positions);
  gemm256<short, 1><<<dim3(4, 128), dim3(512), 131072, stream>>>(cbuf, wkuT, kvup, nullptr, 1024, 32768, 512);

  // ---- attention (v3: 256-thread blocks, 3/CU co-resident) ----
  mla_attn3<<<1024, dim3(256), 0, stream>>>(q_b, kvup, krope, attn_o);

  // ---- output projection (gemm256, split-K=2) ----
  gemm256<float, 2><<<dim3(4, 28, 2), dim3(512), 131072, stream>>>(attn_o, woT, (float*)nullptr, pWo, 1024, 7168, 16384);
  reduceN<2><<<2048, blk, 0, stream>>>(pWo, (float*)d_out, 1024*7168/4, 1024*7168/4);
}

// Round 16
// 956.843 us; speedup vs baseline: 1.7030x; 1.7030x over previous
//
#include <hip/hip_runtime.h>
#include <hip/hip_bf16.h>
#include <math.h>

typedef __attribute__((ext_vector_type(4))) float f32x4;
typedef __attribute__((ext_vector_type(8))) short bf16x8;
typedef __attribute__((ext_vector_type(4))) short bf16x4;

static __device__ __forceinline__ float bf2f(short u){
  unsigned int i = ((unsigned int)(unsigned short)u) << 16;
  return __builtin_bit_cast(float, i);
}
static __device__ __forceinline__ short f2bf(float f){
  unsigned int u = __builtin_bit_cast(unsigned int, f);
  u += 0x7FFFu + ((u >> 16) & 1u);   // RNE
  return (short)(u >> 16);
}

#define GLD16(g, l) __builtin_amdgcn_global_load_lds(                         \
    (const __attribute__((address_space(1))) void*)(g),                       \
    (__attribute__((address_space(3))) void*)(l), 16, 0, 0)

// ---------------------------------------------------------------------------
// gemm256 (round-8 proven best): 256x256 tile, BK=32, 8 waves (2m x 4n),
// per-wave 128x64. 4-slot LDS ring (128 KB), prefetch 3 tiles ahead via
// global_load_lds; drain-aware counted vmcnt (8/4/0) + raw s_barrier.
// T2 swizzle via pre-swizzled global source. T5 setprio.
// ---------------------------------------------------------------------------
template<typename CT, int SPLITS>
__global__ __launch_bounds__(512, 2) void gemm256(const short* __restrict__ A,
                                                  const short* __restrict__ BT,
                                                  CT* __restrict__ C,
                                                  float* __restrict__ P,
                                                  int M, int N, int K)
{
  extern __shared__ __align__(16) char smem[];   // 4 slots x (16KB A + 16KB B)
  const int tid = threadIdx.x;
  const int w = tid >> 6, lane = tid & 63;
  const int wm = w >> 2, wn = w & 3;
  const int g = lane >> 4, l16 = lane & 15;

  const int per_z = gridDim.x * gridDim.y;
  const int F = (blockIdx.z * gridDim.y + blockIdx.y) * gridDim.x + blockIdx.x;
  const int nwgF = per_z * gridDim.z;
  const int cpxF = nwgF >> 3;
  const int T = (F & 7) * cpxF + (F >> 3);
  const int zz = T / per_z, tt = T % per_z;
  const int m0 = (tt & 3) * 256;          // gridDim.x == 4 (M = 1024)
  const int n0 = (tt >> 2) * 256;

  const int Ks   = K / SPLITS;
  const int kbeg = zz * Ks;
  const int NT   = Ks >> 5;               // K-tiles of 32

  const int gg = (lane & 3) ^ ((lane >> 2) & 3) ^ ((lane >> 4) & 1);
  const short* aSrc[2]; const short* bSrc[2];
  int ldsOff[2];
  #pragma unroll
  for (int j = 0; j < 2; j++){
    int r = (w + j*8)*16 + (lane >> 2);
    aSrc[j] = A  + (size_t)(m0 + r) * K + kbeg + gg*8;
    bSrc[j] = BT + (size_t)(n0 + r) * K + kbeg + gg*8;
    ldsOff[j] = (w + j*8) * 1024;
  }

  const int sw = ((g ^ (l16 & 3) ^ ((l16 >> 2) & 1)) << 4);

  f32x4 acc[8][4];
  #pragma unroll
  for (int i = 0; i < 8; i++)
    #pragma unroll
    for (int j = 0; j < 4; j++) acc[i][j] = (f32x4){0.f,0.f,0.f,0.f};

  auto stage = [&](int b, int t){
    const int koff = t * 32;              // shorts
    char* dst = smem + b * 32768;
    #pragma unroll
    for (int j = 0; j < 2; j++){
      GLD16(aSrc[j] + koff, dst + ldsOff[j]);
      GLD16(bSrc[j] + koff, dst + 16384 + ldsOff[j]);
    }
  };

  auto wait_pub = [&](int ahead){       // ahead = # tiles staged beyond t
    if (ahead >= 3)      asm volatile("s_waitcnt vmcnt(8)" ::: "memory");
    else if (ahead == 2) asm volatile("s_waitcnt vmcnt(4)" ::: "memory");
    else                 asm volatile("s_waitcnt vmcnt(0)" ::: "memory");
    __builtin_amdgcn_s_barrier();
    asm volatile("" ::: "memory");
  };

  stage(0, 0);
  if (NT > 1) stage(1, 1);
  if (NT > 2) stage(2, 2);
  wait_pub(NT - 1 >= 2 ? (NT > 2 ? 3 : 2) : 1);

  const int arow = wm*128 + l16;          // + mi*16
  const int brow = wn*64  + l16;          // + ni*16

  for (int t = 0; t < NT; t++){
    const int sl = t & 3;
    if (t + 3 < NT) stage((t + 3) & 3, t + 3);

    const char* base = smem + sl * 32768;
    bf16x8 a[8], bb[4];
    #pragma unroll
    for (int mi = 0; mi < 8; mi++)
      a[mi] = *reinterpret_cast<const bf16x8*>(base + (arow + mi*16)*64 + sw);
    #pragma unroll
    for (int ni = 0; ni < 4; ni++)
      bb[ni] = *reinterpret_cast<const bf16x8*>(base + 16384 + (brow + ni*16)*64 + sw);

    __builtin_amdgcn_s_setprio(1);
    #pragma unroll
    for (int mi = 0; mi < 8; mi++)
      #pragma unroll
      for (int ni = 0; ni < 4; ni++)
        acc[mi][ni] = __builtin_amdgcn_mfma_f32_16x16x32_bf16(a[mi], bb[ni], acc[mi][ni], 0, 0, 0);
    __builtin_amdgcn_s_setprio(0);

    wait_pub(NT - 1 - t);
  }

  #pragma unroll
  for (int mi = 0; mi < 8; mi++){
    int row = m0 + wm*128 + mi*16 + g*4;
    #pragma unroll
    for (int ni = 0; ni < 4; ni++){
      int col = n0 + wn*64 + ni*16 + l16;
      #pragma unroll
      for (int r = 0; r < 4; r++){
        if constexpr (SPLITS > 1){
          P[(size_t)zz*M*N + (size_t)(row+r)*N + col] = acc[mi][ni][r];
        } else if constexpr (sizeof(CT) == 4){
          C[(size_t)(row+r)*N + col] = acc[mi][ni][r];
        } else {
          C[(size_t)(row+r)*N + col] = f2bf(acc[mi][ni][r]);
        }
      }
    }
  }
}

// ---------------------------------------------------------------------------
// Old 128x128 kernel (kept for the ragged-N down-projection, N=2112).
// ---------------------------------------------------------------------------
template<typename CT, int SPLITS>
__global__ __launch_bounds__(256) void gemm_bt(const short* __restrict__ A,
                                               const short* __restrict__ BT,
                                               CT* __restrict__ C,
                                               float* __restrict__ P,
                                               int M, int N, int K)
{
  __shared__ __align__(16) short As[2][128*32];
  __shared__ __align__(16) short Bs[2][128*32];
  const int tid = threadIdx.x;
  const int f   = blockIdx.y * 8 + blockIdx.x;
  const int nwg = 8 * gridDim.y;
  const int cpx = nwg >> 3;
  const int t   = (f & 7) * cpx + (f >> 3);
  const int m0  = (t & 7) * 128;
  const int n0  = (t >> 3) * 128;
  const int w = tid >> 6, lane = tid & 63;
  const int wr = w >> 1, wc = w & 1;
  const int g = lane >> 4, l16 = lane & 15;

  const int Ks   = K / SPLITS;
  const int kbeg = blockIdx.z * Ks;
  const int kend = kbeg + Ks;

  const int sr = lane >> 2;
  const int kc = (lane & 3) << 3;
  const int arow0 = m0 + w*16 + sr;
  const int arow1 = m0 + (w+4)*16 + sr;
  int brow0 = n0 + w*16 + sr;      if (brow0 >= N) brow0 = N - 1;
  int brow1 = n0 + (w+4)*16 + sr;  if (brow1 >= N) brow1 = N - 1;
  const short* aG0 = A  + (size_t)arow0 * K + kc;
  const short* aG1 = A  + (size_t)arow1 * K + kc;
  const short* bG0 = BT + (size_t)brow0 * K + kc;
  const short* bG1 = BT + (size_t)brow1 * K + kc;
  char* aL = (char*)As;
  char* bL = (char*)Bs;

  auto stage = [&](int buf, int k0){
    char* ab = aL + buf*8192;
    char* bb = bL + buf*8192;
    GLD16(aG0 + k0, ab + (w  )*1024);
    GLD16(aG1 + k0, ab + (w+4)*1024);
    GLD16(bG0 + k0, bb + (w  )*1024);
    GLD16(bG1 + k0, bb + (w+4)*1024);
  };

  f32x4 acc[4][4];
  #pragma unroll
  for (int i=0;i<4;i++)
    #pragma unroll
    for (int j=0;j<4;j++) acc[i][j] = (f32x4){0.f,0.f,0.f,0.f};

  stage(0, kbeg);
  __syncthreads();

  int cur = 0;
  for (int k0 = kbeg; k0 < kend; k0 += 32){
    if (k0 + 32 < kend) stage(cur ^ 1, k0 + 32);

    const char* ar = aL + cur*8192;
    const char* br = bL + cur*8192;
    bf16x8 af[4], bfm[4];
    #pragma unroll
    for (int mi=0;mi<4;mi++){
      int row = wr*64 + mi*16 + l16;
      af[mi] = *reinterpret_cast<const bf16x8*>(ar + row*64 + g*16);
    }
    #pragma unroll
    for (int ni=0;ni<4;ni++){
      int row = wc*64 + ni*16 + l16;
      bfm[ni] = *reinterpret_cast<const bf16x8*>(br + row*64 + g*16);
    }
    #pragma unroll
    for (int mi=0;mi<4;mi++)
      #pragma unroll
      for (int ni=0;ni<4;ni++)
        acc[mi][ni] = __builtin_amdgcn_mfma_f32_16x16x32_bf16(af[mi], bfm[ni], acc[mi][ni], 0, 0, 0);

    __syncthreads();
    cur ^= 1;
  }

  #pragma unroll
  for (int mi=0;mi<4;mi++){
    int row = m0 + wr*64 + mi*16 + g*4;
    #pragma unroll
    for (int ni=0;ni<4;ni++){
      int col = n0 + wc*64 + ni*16 + l16;
      if (col < N){
        #pragma unroll
        for (int r=0;r<4;r++){
          if constexpr (SPLITS > 1){
            P[(size_t)blockIdx.z*M*N + (size_t)(row+r)*N + col] = acc[mi][ni][r];
          } else if constexpr (sizeof(CT) == 4){
            C[(size_t)(row+r)*N + col] = acc[mi][ni][r];
          } else {
            C[(size_t)(row+r)*N + col] = f2bf(acc[mi][ni][r]);
          }
        }
      }
    }
  }
}

// ---------------------------------------------------------------------------
template<int NP>
__global__ __launch_bounds__(256) void reduceN(const float* __restrict__ p,
                                               float* __restrict__ out,
                                               int n4, int mn4)
{
  int i = blockIdx.x * 256 + threadIdx.x;
  const int stride = gridDim.x * 256;
  for (; i < n4; i += stride){
    f32x4 s = reinterpret_cast<const f32x4*>(p)[i];
    #pragma unroll
    for (int z = 1; z < NP; z++)
      s = s + reinterpret_cast<const f32x4*>(p)[(size_t)z*mn4 + i];
    reinterpret_cast<f32x4*>(out)[i] = s;
  }
}

// ---------------------------------------------------------------------------
__global__ __launch_bounds__(256) void transpose_f32_bf16(const float* __restrict__ src,
                                                          short* __restrict__ dst,
                                                          int R, int C)
{
  __shared__ float tl[64][68];
  const int tid = threadIdx.x;
  const int r0 = blockIdx.y * 64, c0 = blockIdx.x * 64;
  {
    const int lr = tid >> 4, lc = (tid & 15) << 2;
    #pragma unroll
    for (int p = 0; p < 4; p++){
      int row = p*16 + lr;
      f32x4 v = *reinterpret_cast<const f32x4*>(src + (size_t)(r0+row)*C + c0 + lc);
      *reinterpret_cast<f32x4*>(&tl[row][lc]) = v;
    }
  }
  __syncthreads();
  {
    const int n = tid >> 2, ks = (tid & 3) << 4;
    short tmp[16];
    #pragma unroll
    for (int j = 0; j < 16; j++) tmp[j] = f2bf(tl[ks + j][n]);
    short* d = dst + (size_t)(c0+n)*R + r0 + ks;
    *reinterpret_cast<bf16x8*>(d)     = *reinterpret_cast<bf16x8*>(&tmp[0]);
    *reinterpret_cast<bf16x8*>(d + 8) = *reinterpret_cast<bf16x8*>(&tmp[8]);
  }
}

// ---------------------------------------------------------------------------
__global__ __launch_bounds__(256) void conv_f32_bf16(const float* __restrict__ src,
                                                     short* __restrict__ dst, int n4)
{
  int i = blockIdx.x * 256 + threadIdx.x;
  const int stride = gridDim.x * 256;
  for (; i < n4; i += stride){
    f32x4 v = reinterpret_cast<const f32x4*>(src)[i];
    bf16x4 h; h[0]=f2bf(v[0]); h[1]=f2bf(v[1]); h[2]=f2bf(v[2]); h[3]=f2bf(v[3]);
    reinterpret_cast<bf16x4*>(dst)[i] = h;
  }
}

// ---------------------------------------------------------------------------
__device__ __forceinline__ void yarn_cs(int pos, int j, float& c, float& s){
  const double dim = 64.0;
  double pf = pow(10000.0, (2.0*(double)j)/dim);
  double inv_extra = 1.0/pf;
  double inv_inter = inv_extra/40.0;
  double lo = floor(dim*log(4096.0/(32.0*2.0*M_PI))/(2.0*log(10000.0)));
  double hi = ceil (dim*log(4096.0/(       2.0*M_PI))/(2.0*log(10000.0)));
  if (lo < 0.0) lo = 0.0;
  if (hi > dim - 1.0) hi = dim - 1.0;
  double denom = hi - lo; if (denom < 0.001) denom = 0.001;
  double ramp = ((double)j - lo)/denom;
  ramp = ramp < 0.0 ? 0.0 : (ramp > 1.0 ? 1.0 : ramp);
  double mask = 1.0 - ramp;
  float invf = (float)(inv_inter*(1.0 - mask) + inv_extra*mask);
  float ang = (float)pos * invf;
  c = cosf(ang); s = sinf(ang);
}

// ---------------------------------------------------------------------------
__global__ __launch_bounds__(256) void mla_rope_q(short* __restrict__ qb,
                                                  const int* __restrict__ positions)
{
  const int t = blockIdx.x;
  __shared__ float cs[32], sn[32];
  if (threadIdx.x < 32){
    float c, s; yarn_cs(positions[t], threadIdx.x, c, s);
    cs[threadIdx.x] = c; sn[threadIdx.x] = s;
  }
  __syncthreads();
  const float f = 0.004510548978043951f;   // 192^-0.5 * 256^-0.5
  short* row = qb + (size_t)t * 24576;
  for (int idx = threadIdx.x; idx < 128*160; idx += 256){
    int n = idx / 160, e = idx % 160;
    short* p = row + n*192;
    if (e < 128){
      p[e] = f2bf(bf2f(p[e]) * f);
    } else {
      int j = e - 128;
      float x1 = bf2f(p[128+j]), x2 = bf2f(p[160+j]);
      p[128+j] = f2bf((x1*cs[j] - x2*sn[j]) * f);
      p[160+j] = f2bf((x2*cs[j] + x1*sn[j]) * f);
    }
  }
}

// ---------------------------------------------------------------------------
// Fused post-down: q-rmsnorm (cols 0..1535 -> qAbf), kv-rmsnorm (1536..2047
// -> cbuf), k-rope (2048..2111 -> krope). One pass over downC.
// ---------------------------------------------------------------------------
__global__ __launch_bounds__(256) void mla_post(const float* __restrict__ dc,
                                                const float* __restrict__ qs,
                                                const float* __restrict__ kvs,
                                                const int* __restrict__ positions,
                                                short* __restrict__ qAbf,
                                                short* __restrict__ cbuf,
                                                short* __restrict__ krope)
{
  const int t = blockIdx.x;
  const float* row = dc + (size_t)t * 2112;
  float s1 = 0.f, s2 = 0.f;
  for (int i = threadIdx.x; i < 1536; i += 256){ float v = row[i]; s1 += v*v; }
  for (int i = threadIdx.x; i < 512;  i += 256){ float v = row[1536+i]; s2 += v*v; }
  #pragma unroll
  for (int off = 32; off >= 1; off >>= 1){ s1 += __shfl_xor(s1, off); s2 += __shfl_xor(s2, off); }
  __shared__ float red[8];
  if ((threadIdx.x & 63) == 0){ red[threadIdx.x >> 6] = s1; red[4 + (threadIdx.x >> 6)] = s2; }
  __syncthreads();
  s1 = red[0]+red[1]+red[2]+red[3];
  s2 = red[4]+red[5]+red[6]+red[7];
  const float rs1 = 1.0f / sqrtf(s1 / 1536.f + 1e-6f);
  const float rs2 = 1.0f / sqrtf(s2 / 512.f  + 1e-6f);
  for (int i = threadIdx.x; i < 1536; i += 256)
    qAbf[(size_t)t*1536 + i] = f2bf(row[i] * rs1 * qs[i]);
  for (int i = threadIdx.x; i < 512; i += 256)
    cbuf[(size_t)t*512 + i] = f2bf(row[1536+i] * rs2 * kvs[i]);
  if (threadIdx.x < 32){
    int j = threadIdx.x;
    float c, s; yarn_cs(positions[t], j, c, s);
    float x1 = row[2048 + j], x2 = row[2080 + j];
    krope[(size_t)t*64 + j]      = f2bf(x1*c - x2*s);
    krope[(size_t)t*64 + 32 + j] = f2bf(x2*c + x1*s);
  }
}

// ---------------------------------------------------------------------------
// Flash attention v3 (ROUND 16): identical to round 15 EXCEPT the missing
// __launch_bounds__(256) — without it hipcc assumed 1024-thread blocks and
// capped VGPR at 64 (massive spill, 877 us). With (256) the allocator is
// free (natural ~150 VGPR, no spill); 4-wave blocks, 48 KB LDS -> 3
// blocks/CU co-resident for cross-block latency hiding.
// ---------------------------------------------------------------------------
__global__ __launch_bounds__(256) void mla_attn3(const short* __restrict__ qb,
                                                 const short* __restrict__ kvup,
                                                 const short* __restrict__ krope,
                                                 short* __restrict__ attn_out)
{
  const int f = blockIdx.x;           // 0..1023
  const int xcd = f & 7, pos = f >> 3;      // pos 0..127
  const int n  = xcd*16 + (pos >> 3);       // head; 8 pair-blocks of a head same XCD
  const int pair = pos & 7;                 // 0..7
  const int tid = threadIdx.x, w = tid >> 6, lane = tid & 63;
  const int g = lane >> 4, l16 = lane & 15;

  __shared__ __align__(16) short Klds[64*192];    // 24 KB
  __shared__ __align__(16) short Vlds[128*64];    // 16 KB
  __shared__ __align__(16) short Plds[4][16*64];  // 8 KB
  char* KB = (char*)Klds; char* VB = (char*)Vlds; char* PB = (char*)Plds[w];

  bf16x8 kpre[6], vpre[4];

  int kS[6], kHB[6];
  #pragma unroll
  for (int c=0;c<6;c++){
    int lin = c*256 + tid;
    kS[c] = lin / 24; kHB[c] = (lin % 24) * 8;
  }
  int vS[4], vVB[4], vROT[4];
  #pragma unroll
  for (int c=0;c<4;c++){
    int lin = c*256 + tid;
    vS[c] = lin >> 4; vVB[c] = (lin & 15) << 3; vROT[c] = (lin & 15) & 7;
  }

  auto stage_load = [&](int S0){
    #pragma unroll
    for (int c=0;c<6;c++){
      const short* src = (kHB[c] < 128)
        ? kvup  + (size_t)(S0 + kS[c])*32768 + n*256 + kHB[c]
        : krope + (size_t)(S0 + kS[c])*64 + (kHB[c]-128);
      kpre[c] = *reinterpret_cast<const bf16x8*>(src);
    }
    #pragma unroll
    for (int c=0;c<4;c++)
      vpre[c] = *reinterpret_cast<const bf16x8*>(kvup + (size_t)(S0 + vS[c])*32768 + n*256 + 128 + vVB[c]);
  };
  auto stage_write = [&](){
    #pragma unroll
    for (int c=0;c<6;c++){
      unsigned byte = (unsigned)(kS[c]*384 + kHB[c]*2) ^ ((unsigned)(kS[c]&7)<<4);
      *reinterpret_cast<bf16x8*>(KB + byte) = kpre[c];
    }
    #pragma unroll
    for (int c=0;c<4;c++){
      #pragma unroll
      for (int i=0;i<8;i++){
        int v = vVB[c] + i;
        unsigned byte = (unsigned)(v*128 + ((vS[c]*2 + vROT[c]*16) & 127));
        *reinterpret_cast<short*>(VB + byte) = vpre[c][i];
      }
    }
  };

  stage_load(0);
  stage_write();
  __syncthreads();

  #pragma unroll
  for (int p = 0; p < 2; p++){
    const int qtl = p ? (15 - pair) : pair;   // 64-row tile index 0..15
    const int t0 = qtl * 64;
    const int last = qtl;                     // sb = 0..qtl

    bf16x8 qf[6];
    {
      const size_t qrow = (size_t)(t0 + w*16 + l16) * 24576 + (size_t)n * 192;
      #pragma unroll
      for (int c=0;c<6;c++)
        qf[c] = *reinterpret_cast<const bf16x8*>(qb + qrow + c*32 + g*8);
    }
    f32x4 o[8];
    #pragma unroll
    for (int i=0;i<8;i++) o[i] = (f32x4){0.f,0.f,0.f,0.f};
    float m[4], l[4];
    #pragma unroll
    for (int r=0;r<4;r++){ m[r] = -1e30f; l[r] = 0.f; }

    for (int sb = 0; sb <= last; sb++){
      const bool more = (sb < last) || (p == 0);
      if (more) stage_load((sb < last) ? (sb+1)*64 : 0);

      f32x4 S[4];
      __builtin_amdgcn_s_setprio(1);
      #pragma unroll
      for (int st=0; st<4; st++){
        f32x4 sacc = (f32x4){0.f,0.f,0.f,0.f};
        int srow = st*16 + l16;
        #pragma unroll
        for (int c=0;c<6;c++){
          unsigned byte = (unsigned)(srow*384 + c*64 + g*16) ^ ((unsigned)(srow&7)<<4);
          bf16x8 kf = *reinterpret_cast<const bf16x8*>(KB + byte);
          sacc = __builtin_amdgcn_mfma_f32_16x16x32_bf16(qf[c], kf, sacc, 0, 0, 0);
        }
        S[st] = sacc;
      }
      __builtin_amdgcn_s_setprio(0);

      if (sb == qtl){                          // diagonal tile: causal mask
        #pragma unroll
        for (int st=0;st<4;st++){
          int sg = sb*64 + st*16 + l16;
          #pragma unroll
          for (int r=0;r<4;r++){
            int qg = t0 + w*16 + g*4 + r;
            if (sg > qg) S[st][r] = -1e30f;
          }
        }
      }
      float alpha[4];
      #pragma unroll
      for (int r=0;r<4;r++){
        float mx = fmaxf(fmaxf(S[0][r],S[1][r]), fmaxf(S[2][r],S[3][r]));
        #pragma unroll
        for (int off=8; off>=1; off>>=1) mx = fmaxf(mx, __shfl_xor(mx, off));
        float mnew = fmaxf(m[r], mx);
        alpha[r] = __expf(m[r] - mnew);
        m[r] = mnew;
        l[r] *= alpha[r];
      }
      #pragma unroll
      for (int st=0;st<4;st++)
        #pragma unroll
        for (int r=0;r<4;r++)
          S[st][r] = __expf(S[st][r] - m[r]);
      #pragma unroll
      for (int r=0;r<4;r++){
        float sum = S[0][r]+S[1][r]+S[2][r]+S[3][r];
        #pragma unroll
        for (int off=8; off>=1; off>>=1) sum += __shfl_xor(sum, off);
        l[r] += sum;
      }
      #pragma unroll
      for (int vt=0; vt<8; vt++)
        #pragma unroll
        for (int r=0;r<4;r++) o[vt][r] *= alpha[r];

      #pragma unroll
      for (int st=0;st<4;st++){
        #pragma unroll
        for (int r=0;r<4;r++){
          int qrow = g*4 + r, scol = st*16 + l16;
          unsigned byte = (unsigned)(qrow*128 + scol*2) ^ ((unsigned)(qrow&7)<<4);
          *reinterpret_cast<short*>(PB + byte) = f2bf(S[st][r]);
        }
      }
      bf16x8 pf[2];
      #pragma unroll
      for (int c=0;c<2;c++){
        unsigned byte = (unsigned)(l16*128 + (c*32 + g*8)*2) ^ ((unsigned)(l16&7)<<4);
        pf[c] = *reinterpret_cast<const bf16x8*>(PB + byte);
      }
      __builtin_amdgcn_s_setprio(1);
      #pragma unroll
      for (int vt=0; vt<8; vt++){
        #pragma unroll
        for (int c=0;c<2;c++){
          int vrow = vt*16 + l16;
          int rot = (vrow >> 3) & 7;
          unsigned byte = (unsigned)(vrow*128 + ((c*64 + g*16 + rot*16) & 127));
          bf16x8 vf = *reinterpret_cast<const bf16x8*>(VB + byte);
          o[vt] = __builtin_amdgcn_mfma_f32_16x16x32_bf16(pf[c], vf, o[vt], 0, 0, 0);
        }
      }
      __builtin_amdgcn_s_setprio(0);

      if (more){
        __syncthreads();
        stage_write();
        __syncthreads();
      }
    }

    #pragma unroll
    for (int r=0;r<4;r++){
      float inv = 1.f / l[r];
      int t = t0 + w*16 + g*4 + r;
      #pragma unroll
      for (int vt=0;vt<8;vt++){
        int v = vt*16 + l16;
        attn_out[(size_t)t*16384 + n*128 + v] = f2bf(o[vt][r] * inv);
      }
    }
  }
}

// ---------------------------------------------------------------------------
extern "C" void kernel_launch(void* const* d_in, const int* in_sizes, int n_in,
                              void* d_out, int out_size, void* d_ws, size_t ws_size,
                              hipStream_t stream) {
  const float* x            = (const float*)d_in[0];
  const int*   positions    = (const int*)  d_in[1];
  const float* w_q_down     = (const float*)d_in[2];
  const float* q_norm_scale = (const float*)d_in[3];
  const float* w_q_up       = (const float*)d_in[4];
  const float* w_kv_down    = (const float*)d_in[5];
  const float* kv_norm_scale= (const float*)d_in[6];
  const float* w_kv_up      = (const float*)d_in[7];
  const float* w_o          = (const float*)d_in[8];

  char* p = (char*)d_ws;
  short* xbf   = (short*)p; p += (size_t)1024*7168*2;    // 14.7 MB
  short* wdT   = (short*)p; p += (size_t)2112*7168*2;    // 30.3 MB  [2112][7168]
  short* wquT  = (short*)p; p += (size_t)24576*1536*2;   // 75.5 MB
  short* wkuT  = (short*)p; p += (size_t)32768*512*2;    // 33.6 MB
  short* woT   = (short*)p; p += (size_t)7168*16384*2;   // 234.9 MB
  float* downC = (float*)p; p += (size_t)1024*2112*4;    // 8.7 MB
  short* qAbf  = (short*)p; p += (size_t)1024*1536*2;    // 3.1 MB
  short* q_b   = (short*)p; p += (size_t)1024*24576*2;   // 50.3 MB
  short* cbuf  = (short*)p; p += (size_t)1024*512*2;     // 1.0 MB
  short* krope = (short*)p; p += (size_t)1024*64*2;      // 0.13 MB
  short* kvup  = (short*)p; p += (size_t)1024*32768*2;   // 67 MB
  short* attn_o= (short*)p; p += (size_t)1024*16384*2;   // 33.6 MB

  float* pDown = (float*)q_b;     // 4 planes of 1024x2112 f32 (q_b dead here)
  float* pWo   = (float*)d_ws;    // 2 planes of 1024x7168 f32 (prepass bufs dead)

  hipFuncSetAttribute(reinterpret_cast<const void*>(&gemm256<short,1>),
                      hipFuncAttributeMaxDynamicSharedMemorySize, 131072);
  hipFuncSetAttribute(reinterpret_cast<const void*>(&gemm256<float,2>),
                      hipFuncAttributeMaxDynamicSharedMemorySize, 131072);

  dim3 blk(256);
  // ---- prepass: convert + transpose ----
  conv_f32_bf16<<<2048, blk, 0, stream>>>(x, xbf, 1024*7168/4);
  transpose_f32_bf16<<<dim3(24, 112),  blk, 0, stream>>>(w_q_down,  wdT,                     7168, 1536);
  transpose_f32_bf16<<<dim3(9, 112),   blk, 0, stream>>>(w_kv_down, wdT + (size_t)1536*7168, 7168, 576);
  transpose_f32_bf16<<<dim3(384, 24),  blk, 0, stream>>>(w_q_up,    wquT,                    1536, 24576);
  transpose_f32_bf16<<<dim3(512, 8),   blk, 0, stream>>>(w_kv_up,   wkuT,                    512,  32768);
  transpose_f32_bf16<<<dim3(112, 256), blk, 0, stream>>>(w_o,       woT,                     16384, 7168);

  // ---- fused down-proj (old kernel, split-K=4) + fused post ----
  gemm_bt<float, 4><<<dim3(8, 17, 4), blk, 0, stream>>>(xbf, wdT, (float*)nullptr, pDown, 1024, 2112, 7168);
  reduceN<4><<<1024, blk, 0, stream>>>(pDown, downC, 1024*2112/4, 1024*2112/4);
  mla_post<<<1024, blk, 0, stream>>>(downC, q_norm_scale, kv_norm_scale, positions, qAbf, cbuf, krope);

  // ---- up-projections (gemm256, round-8 config) ----
  gemm256<short, 1><<<dim3(4, 96), dim3(512), 131072, stream>>>(qAbf, wquT, q_b, nullptr, 1024, 24576, 1536);
  mla_rope_q<<<1024, blk, 0, stream>>>(q_b, positions);
  gemm256<short, 1><<<dim3(4, 128), dim3(512), 131072, stream>>>(cbuf, wkuT, kvup, nullptr, 1024, 32768, 512);

  // ---- attention (v3 + proper launch bounds) ----
  mla_attn3<<<1024, dim3(256), 0, stream>>>(q_b, kvup, krope, attn_o);

  // ---- output projection (gemm256, split-K=2) ----
  gemm256<float, 2><<<dim3(4, 28, 2), dim3(512), 131072, stream>>>(attn_o, woT, (float*)nullptr, pWo, 1024, 7168, 16384);
  reduceN<2><<<2048, blk, 0, stream>>>(pWo, (float*)d_out, 1024*7168/4, 1024*7168/4);
}

// Round 17
// 880.016 us; speedup vs baseline: 1.8517x; 1.0873x over previous
//
#include <hip/hip_runtime.h>
#include <hip/hip_bf16.h>
#include <math.h>

typedef __attribute__((ext_vector_type(4))) float f32x4;
typedef __attribute__((ext_vector_type(8))) short bf16x8;
typedef __attribute__((ext_vector_type(4))) short bf16x4;

static __device__ __forceinline__ float bf2f(short u){
  unsigned int i = ((unsigned int)(unsigned short)u) << 16;
  return __builtin_bit_cast(float, i);
}
static __device__ __forceinline__ short f2bf(float f){
  unsigned int u = __builtin_bit_cast(unsigned int, f);
  u += 0x7FFFu + ((u >> 16) & 1u);   // RNE
  return (short)(u >> 16);
}

#define GLD16(g, l) __builtin_amdgcn_global_load_lds(                         \
    (const __attribute__((address_space(1))) void*)(g),                       \
    (__attribute__((address_space(3))) void*)(l), 16, 0, 0)

// ---------------------------------------------------------------------------
// gemm256 (round-8 proven best): 256x256 tile, BK=32, 8 waves (2m x 4n),
// per-wave 128x64. 4-slot LDS ring (128 KB), prefetch 3 tiles ahead via
// global_load_lds; drain-aware counted vmcnt (8/4/0) + raw s_barrier.
// T2 swizzle via pre-swizzled global source. T5 setprio.
// ---------------------------------------------------------------------------
template<typename CT, int SPLITS>
__global__ __launch_bounds__(512, 2) void gemm256(const short* __restrict__ A,
                                                  const short* __restrict__ BT,
                                                  CT* __restrict__ C,
                                                  float* __restrict__ P,
                                                  int M, int N, int K)
{
  extern __shared__ __align__(16) char smem[];   // 4 slots x (16KB A + 16KB B)
  const int tid = threadIdx.x;
  const int w = tid >> 6, lane = tid & 63;
  const int wm = w >> 2, wn = w & 3;
  const int g = lane >> 4, l16 = lane & 15;

  const int per_z = gridDim.x * gridDim.y;
  const int F = (blockIdx.z * gridDim.y + blockIdx.y) * gridDim.x + blockIdx.x;
  const int nwgF = per_z * gridDim.z;
  const int cpxF = nwgF >> 3;
  const int T = (F & 7) * cpxF + (F >> 3);
  const int zz = T / per_z, tt = T % per_z;
  const int m0 = (tt & 3) * 256;          // gridDim.x == 4 (M = 1024)
  const int n0 = (tt >> 2) * 256;

  const int Ks   = K / SPLITS;
  const int kbeg = zz * Ks;
  const int NT   = Ks >> 5;               // K-tiles of 32

  const int gg = (lane & 3) ^ ((lane >> 2) & 3) ^ ((lane >> 4) & 1);
  const short* aSrc[2]; const short* bSrc[2];
  int ldsOff[2];
  #pragma unroll
  for (int j = 0; j < 2; j++){
    int r = (w + j*8)*16 + (lane >> 2);
    aSrc[j] = A  + (size_t)(m0 + r) * K + kbeg + gg*8;
    bSrc[j] = BT + (size_t)(n0 + r) * K + kbeg + gg*8;
    ldsOff[j] = (w + j*8) * 1024;
  }

  const int sw = ((g ^ (l16 & 3) ^ ((l16 >> 2) & 1)) << 4);

  f32x4 acc[8][4];
  #pragma unroll
  for (int i = 0; i < 8; i++)
    #pragma unroll
    for (int j = 0; j < 4; j++) acc[i][j] = (f32x4){0.f,0.f,0.f,0.f};

  auto stage = [&](int b, int t){
    const int koff = t * 32;              // shorts
    char* dst = smem + b * 32768;
    #pragma unroll
    for (int j = 0; j < 2; j++){
      GLD16(aSrc[j] + koff, dst + ldsOff[j]);
      GLD16(bSrc[j] + koff, dst + 16384 + ldsOff[j]);
    }
  };

  auto wait_pub = [&](int ahead){       // ahead = # tiles staged beyond t
    if (ahead >= 3)      asm volatile("s_waitcnt vmcnt(8)" ::: "memory");
    else if (ahead == 2) asm volatile("s_waitcnt vmcnt(4)" ::: "memory");
    else                 asm volatile("s_waitcnt vmcnt(0)" ::: "memory");
    __builtin_amdgcn_s_barrier();
    asm volatile("" ::: "memory");
  };

  stage(0, 0);
  if (NT > 1) stage(1, 1);
  if (NT > 2) stage(2, 2);
  wait_pub(NT - 1 >= 2 ? (NT > 2 ? 3 : 2) : 1);

  const int arow = wm*128 + l16;          // + mi*16
  const int brow = wn*64  + l16;          // + ni*16

  for (int t = 0; t < NT; t++){
    const int sl = t & 3;
    if (t + 3 < NT) stage((t + 3) & 3, t + 3);

    const char* base = smem + sl * 32768;
    bf16x8 a[8], bb[4];
    #pragma unroll
    for (int mi = 0; mi < 8; mi++)
      a[mi] = *reinterpret_cast<const bf16x8*>(base + (arow + mi*16)*64 + sw);
    #pragma unroll
    for (int ni = 0; ni < 4; ni++)
      bb[ni] = *reinterpret_cast<const bf16x8*>(base + 16384 + (brow + ni*16)*64 + sw);

    __builtin_amdgcn_s_setprio(1);
    #pragma unroll
    for (int mi = 0; mi < 8; mi++)
      #pragma unroll
      for (int ni = 0; ni < 4; ni++)
        acc[mi][ni] = __builtin_amdgcn_mfma_f32_16x16x32_bf16(a[mi], bb[ni], acc[mi][ni], 0, 0, 0);
    __builtin_amdgcn_s_setprio(0);

    wait_pub(NT - 1 - t);
  }

  #pragma unroll
  for (int mi = 0; mi < 8; mi++){
    int row = m0 + wm*128 + mi*16 + g*4;
    #pragma unroll
    for (int ni = 0; ni < 4; ni++){
      int col = n0 + wn*64 + ni*16 + l16;
      #pragma unroll
      for (int r = 0; r < 4; r++){
        if constexpr (SPLITS > 1){
          P[(size_t)zz*M*N + (size_t)(row+r)*N + col] = acc[mi][ni][r];
        } else if constexpr (sizeof(CT) == 4){
          C[(size_t)(row+r)*N + col] = acc[mi][ni][r];
        } else {
          C[(size_t)(row+r)*N + col] = f2bf(acc[mi][ni][r]);
        }
      }
    }
  }
}

// ---------------------------------------------------------------------------
// Old 128x128 kernel (kept for the ragged-N down-projection, N=2112).
// ---------------------------------------------------------------------------
template<typename CT, int SPLITS>
__global__ __launch_bounds__(256) void gemm_bt(const short* __restrict__ A,
                                               const short* __restrict__ BT,
                                               CT* __restrict__ C,
                                               float* __restrict__ P,
                                               int M, int N, int K)
{
  __shared__ __align__(16) short As[2][128*32];
  __shared__ __align__(16) short Bs[2][128*32];
  const int tid = threadIdx.x;
  const int f   = blockIdx.y * 8 + blockIdx.x;
  const int nwg = 8 * gridDim.y;
  const int cpx = nwg >> 3;
  const int t   = (f & 7) * cpx + (f >> 3);
  const int m0  = (t & 7) * 128;
  const int n0  = (t >> 3) * 128;
  const int w = tid >> 6, lane = tid & 63;
  const int wr = w >> 1, wc = w & 1;
  const int g = lane >> 4, l16 = lane & 15;

  const int Ks   = K / SPLITS;
  const int kbeg = blockIdx.z * Ks;
  const int kend = kbeg + Ks;

  const int sr = lane >> 2;
  const int kc = (lane & 3) << 3;
  const int arow0 = m0 + w*16 + sr;
  const int arow1 = m0 + (w+4)*16 + sr;
  int brow0 = n0 + w*16 + sr;      if (brow0 >= N) brow0 = N - 1;
  int brow1 = n0 + (w+4)*16 + sr;  if (brow1 >= N) brow1 = N - 1;
  const short* aG0 = A  + (size_t)arow0 * K + kc;
  const short* aG1 = A  + (size_t)arow1 * K + kc;
  const short* bG0 = BT + (size_t)brow0 * K + kc;
  const short* bG1 = BT + (size_t)brow1 * K + kc;
  char* aL = (char*)As;
  char* bL = (char*)Bs;

  auto stage = [&](int buf, int k0){
    char* ab = aL + buf*8192;
    char* bb = bL + buf*8192;
    GLD16(aG0 + k0, ab + (w  )*1024);
    GLD16(aG1 + k0, ab + (w+4)*1024);
    GLD16(bG0 + k0, bb + (w  )*1024);
    GLD16(bG1 + k0, bb + (w+4)*1024);
  };

  f32x4 acc[4][4];
  #pragma unroll
  for (int i=0;i<4;i++)
    #pragma unroll
    for (int j=0;j<4;j++) acc[i][j] = (f32x4){0.f,0.f,0.f,0.f};

  stage(0, kbeg);
  __syncthreads();

  int cur = 0;
  for (int k0 = kbeg; k0 < kend; k0 += 32){
    if (k0 + 32 < kend) stage(cur ^ 1, k0 + 32);

    const char* ar = aL + cur*8192;
    const char* br = bL + cur*8192;
    bf16x8 af[4], bfm[4];
    #pragma unroll
    for (int mi=0;mi<4;mi++){
      int row = wr*64 + mi*16 + l16;
      af[mi] = *reinterpret_cast<const bf16x8*>(ar + row*64 + g*16);
    }
    #pragma unroll
    for (int ni=0;ni<4;ni++){
      int row = wc*64 + ni*16 + l16;
      bfm[ni] = *reinterpret_cast<const bf16x8*>(br + row*64 + g*16);
    }
    #pragma unroll
    for (int mi=0;mi<4;mi++)
      #pragma unroll
      for (int ni=0;ni<4;ni++)
        acc[mi][ni] = __builtin_amdgcn_mfma_f32_16x16x32_bf16(af[mi], bfm[ni], acc[mi][ni], 0, 0, 0);

    __syncthreads();
    cur ^= 1;
  }

  #pragma unroll
  for (int mi=0;mi<4;mi++){
    int row = m0 + wr*64 + mi*16 + g*4;
    #pragma unroll
    for (int ni=0;ni<4;ni++){
      int col = n0 + wc*64 + ni*16 + l16;
      if (col < N){
        #pragma unroll
        for (int r=0;r<4;r++){
          if constexpr (SPLITS > 1){
            P[(size_t)blockIdx.z*M*N + (size_t)(row+r)*N + col] = acc[mi][ni][r];
          } else if constexpr (sizeof(CT) == 4){
            C[(size_t)(row+r)*N + col] = acc[mi][ni][r];
          } else {
            C[(size_t)(row+r)*N + col] = f2bf(acc[mi][ni][r]);
          }
        }
      }
    }
  }
}

// ---------------------------------------------------------------------------
template<int NP>
__global__ __launch_bounds__(256) void reduceN(const float* __restrict__ p,
                                               float* __restrict__ out,
                                               int n4, int mn4)
{
  int i = blockIdx.x * 256 + threadIdx.x;
  const int stride = gridDim.x * 256;
  for (; i < n4; i += stride){
    f32x4 s = reinterpret_cast<const f32x4*>(p)[i];
    #pragma unroll
    for (int z = 1; z < NP; z++)
      s = s + reinterpret_cast<const f32x4*>(p)[(size_t)z*mn4 + i];
    reinterpret_cast<f32x4*>(out)[i] = s;
  }
}

// ---------------------------------------------------------------------------
__global__ __launch_bounds__(256) void transpose_f32_bf16(const float* __restrict__ src,
                                                          short* __restrict__ dst,
                                                          int R, int C)
{
  __shared__ float tl[64][68];
  const int tid = threadIdx.x;
  const int r0 = blockIdx.y * 64, c0 = blockIdx.x * 64;
  {
    const int lr = tid >> 4, lc = (tid & 15) << 2;
    #pragma unroll
    for (int p = 0; p < 4; p++){
      int row = p*16 + lr;
      f32x4 v = *reinterpret_cast<const f32x4*>(src + (size_t)(r0+row)*C + c0 + lc);
      *reinterpret_cast<f32x4*>(&tl[row][lc]) = v;
    }
  }
  __syncthreads();
  {
    const int n = tid >> 2, ks = (tid & 3) << 4;
    short tmp[16];
    #pragma unroll
    for (int j = 0; j < 16; j++) tmp[j] = f2bf(tl[ks + j][n]);
    short* d = dst + (size_t)(c0+n)*R + r0 + ks;
    *reinterpret_cast<bf16x8*>(d)     = *reinterpret_cast<bf16x8*>(&tmp[0]);
    *reinterpret_cast<bf16x8*>(d + 8) = *reinterpret_cast<bf16x8*>(&tmp[8]);
  }
}

// ---------------------------------------------------------------------------
__global__ __launch_bounds__(256) void conv_f32_bf16(const float* __restrict__ src,
                                                     short* __restrict__ dst, int n4)
{
  int i = blockIdx.x * 256 + threadIdx.x;
  const int stride = gridDim.x * 256;
  for (; i < n4; i += stride){
    f32x4 v = reinterpret_cast<const f32x4*>(src)[i];
    bf16x4 h; h[0]=f2bf(v[0]); h[1]=f2bf(v[1]); h[2]=f2bf(v[2]); h[3]=f2bf(v[3]);
    reinterpret_cast<bf16x4*>(dst)[i] = h;
  }
}

// ---------------------------------------------------------------------------
__device__ __forceinline__ void yarn_cs(int pos, int j, float& c, float& s){
  const double dim = 64.0;
  double pf = pow(10000.0, (2.0*(double)j)/dim);
  double inv_extra = 1.0/pf;
  double inv_inter = inv_extra/40.0;
  double lo = floor(dim*log(4096.0/(32.0*2.0*M_PI))/(2.0*log(10000.0)));
  double hi = ceil (dim*log(4096.0/(       2.0*M_PI))/(2.0*log(10000.0)));
  if (lo < 0.0) lo = 0.0;
  if (hi > dim - 1.0) hi = dim - 1.0;
  double denom = hi - lo; if (denom < 0.001) denom = 0.001;
  double ramp = ((double)j - lo)/denom;
  ramp = ramp < 0.0 ? 0.0 : (ramp > 1.0 ? 1.0 : ramp);
  double mask = 1.0 - ramp;
  float invf = (float)(inv_inter*(1.0 - mask) + inv_extra*mask);
  float ang = (float)pos * invf;
  c = cosf(ang); s = sinf(ang);
}

// ---------------------------------------------------------------------------
__global__ __launch_bounds__(256) void mla_rope_q(short* __restrict__ qb,
                                                  const int* __restrict__ positions)
{
  const int t = blockIdx.x;
  __shared__ float cs[32], sn[32];
  if (threadIdx.x < 32){
    float c, s; yarn_cs(positions[t], threadIdx.x, c, s);
    cs[threadIdx.x] = c; sn[threadIdx.x] = s;
  }
  __syncthreads();
  const float f = 0.004510548978043951f;   // 192^-0.5 * 256^-0.5
  short* row = qb + (size_t)t * 24576;
  for (int idx = threadIdx.x; idx < 128*160; idx += 256){
    int n = idx / 160, e = idx % 160;
    short* p = row + n*192;
    if (e < 128){
      p[e] = f2bf(bf2f(p[e]) * f);
    } else {
      int j = e - 128;
      float x1 = bf2f(p[128+j]), x2 = bf2f(p[160+j]);
      p[128+j] = f2bf((x1*cs[j] - x2*sn[j]) * f);
      p[160+j] = f2bf((x2*cs[j] + x1*sn[j]) * f);
    }
  }
}

// ---------------------------------------------------------------------------
// Fused post-down: q-rmsnorm (cols 0..1535 -> qAbf), kv-rmsnorm (1536..2047
// -> cbuf), k-rope (2048..2111 -> krope). One pass over downC.
// ---------------------------------------------------------------------------
__global__ __launch_bounds__(256) void mla_post(const float* __restrict__ dc,
                                                const float* __restrict__ qs,
                                                const float* __restrict__ kvs,
                                                const int* __restrict__ positions,
                                                short* __restrict__ qAbf,
                                                short* __restrict__ cbuf,
                                                short* __restrict__ krope)
{
  const int t = blockIdx.x;
  const float* row = dc + (size_t)t * 2112;
  float s1 = 0.f, s2 = 0.f;
  for (int i = threadIdx.x; i < 1536; i += 256){ float v = row[i]; s1 += v*v; }
  for (int i = threadIdx.x; i < 512;  i += 256){ float v = row[1536+i]; s2 += v*v; }
  #pragma unroll
  for (int off = 32; off >= 1; off >>= 1){ s1 += __shfl_xor(s1, off); s2 += __shfl_xor(s2, off); }
  __shared__ float red[8];
  if ((threadIdx.x & 63) == 0){ red[threadIdx.x >> 6] = s1; red[4 + (threadIdx.x >> 6)] = s2; }
  __syncthreads();
  s1 = red[0]+red[1]+red[2]+red[3];
  s2 = red[4]+red[5]+red[6]+red[7];
  const float rs1 = 1.0f / sqrtf(s1 / 1536.f + 1e-6f);
  const float rs2 = 1.0f / sqrtf(s2 / 512.f  + 1e-6f);
  for (int i = threadIdx.x; i < 1536; i += 256)
    qAbf[(size_t)t*1536 + i] = f2bf(row[i] * rs1 * qs[i]);
  for (int i = threadIdx.x; i < 512; i += 256)
    cbuf[(size_t)t*512 + i] = f2bf(row[1536+i] * rs2 * kvs[i]);
  if (threadIdx.x < 32){
    int j = threadIdx.x;
    float c, s; yarn_cs(positions[t], j, c, s);
    float x1 = row[2048 + j], x2 = row[2080 + j];
    krope[(size_t)t*64 + j]      = f2bf(x1*c - x2*s);
    krope[(size_t)t*64 + 32 + j] = f2bf(x2*c + x1*s);
  }
}

// ---------------------------------------------------------------------------
// Flash attention (round-4/8 version, replay-stable — best measured).
// ---------------------------------------------------------------------------
__global__ __launch_bounds__(512) void mla_attn2(const short* __restrict__ qb,
                                                 const short* __restrict__ kvup,
                                                 const short* __restrict__ krope,
                                                 short* __restrict__ attn_out)
{
  const int f = blockIdx.x;
  const int xcd = f & 7, pos = f >> 3;
  const int n  = xcd*16 + (pos >> 2);
  const int pair = pos & 3;
  const int tid = threadIdx.x, w = tid >> 6, lane = tid & 63;
  const int g = lane >> 4, l16 = lane & 15;

  __shared__ __align__(16) short Klds[64*192];
  __shared__ __align__(16) short Vlds[128*64];
  __shared__ __align__(16) short Plds[8][16*64];
  char* KB = (char*)Klds; char* VB = (char*)Vlds; char* PB = (char*)Plds[w];

  bf16x8 kpre[3], vpre[2];

  int kS[3], kHB[3];
  #pragma unroll
  for (int c=0;c<3;c++){
    int lin = c*512 + tid;
    kS[c] = lin / 24; kHB[c] = (lin % 24) * 8;
  }
  int vS[2], vVB[2], vROT[2];
  #pragma unroll
  for (int c=0;c<2;c++){
    int lin = c*512 + tid;
    vS[c] = lin >> 4; vVB[c] = (lin & 15) << 3; vROT[c] = (lin & 15) & 7;
  }

  auto stage_load = [&](int S0){
    #pragma unroll
    for (int c=0;c<3;c++){
      const short* src = (kHB[c] < 128)
        ? kvup  + (size_t)(S0 + kS[c])*32768 + n*256 + kHB[c]
        : krope + (size_t)(S0 + kS[c])*64 + (kHB[c]-128);
      kpre[c] = *reinterpret_cast<const bf16x8*>(src);
    }
    #pragma unroll
    for (int c=0;c<2;c++)
      vpre[c] = *reinterpret_cast<const bf16x8*>(kvup + (size_t)(S0 + vS[c])*32768 + n*256 + 128 + vVB[c]);
  };
  auto stage_write = [&](){
    #pragma unroll
    for (int c=0;c<3;c++){
      unsigned byte = (unsigned)(kS[c]*384 + kHB[c]*2) ^ ((unsigned)(kS[c]&7)<<4);
      *reinterpret_cast<bf16x8*>(KB + byte) = kpre[c];
    }
    #pragma unroll
    for (int c=0;c<2;c++){
      #pragma unroll
      for (int i=0;i<8;i++){
        int v = vVB[c] + i;
        unsigned byte = (unsigned)(v*128 + ((vS[c]*2 + vROT[c]*16) & 127));
        *reinterpret_cast<short*>(VB + byte) = vpre[c][i];
      }
    }
  };

  stage_load(0);
  stage_write();
  __syncthreads();

  #pragma unroll
  for (int p = 0; p < 2; p++){
    const int qtl = p ? (7 - pair) : pair;
    const int t0 = qtl * 128;
    const int last = 2*qtl + 1;

    bf16x8 qf[6];
    {
      const size_t qrow = (size_t)(t0 + w*16 + l16) * 24576 + (size_t)n * 192;
      #pragma unroll
      for (int c=0;c<6;c++)
        qf[c] = *reinterpret_cast<const bf16x8*>(qb + qrow + c*32 + g*8);
    }
    f32x4 o[8];
    #pragma unroll
    for (int i=0;i<8;i++) o[i] = (f32x4){0.f,0.f,0.f,0.f};
    float m[4], l[4];
    #pragma unroll
    for (int r=0;r<4;r++){ m[r] = -1e30f; l[r] = 0.f; }

    for (int sb = 0; sb <= last; sb++){
      const bool more = (sb < last) || (p == 0);
      if (more) stage_load((sb < last) ? (sb+1)*64 : 0);

      f32x4 S[4];
      __builtin_amdgcn_s_setprio(1);
      #pragma unroll
      for (int st=0; st<4; st++){
        f32x4 sacc = (f32x4){0.f,0.f,0.f,0.f};
        int srow = st*16 + l16;
        #pragma unroll
        for (int c=0;c<6;c++){
          unsigned byte = (unsigned)(srow*384 + c*64 + g*16) ^ ((unsigned)(srow&7)<<4);
          bf16x8 kf = *reinterpret_cast<const bf16x8*>(KB + byte);
          sacc = __builtin_amdgcn_mfma_f32_16x16x32_bf16(qf[c], kf, sacc, 0, 0, 0);
        }
        S[st] = sacc;
      }
      __builtin_amdgcn_s_setprio(0);

      if (sb >= 2*qtl){
        #pragma unroll
        for (int st=0;st<4;st++){
          int sg = sb*64 + st*16 + l16;
          #pragma unroll
          for (int r=0;r<4;r++){
            int qg = t0 + w*16 + g*4 + r;
            if (sg > qg) S[st][r] = -1e30f;
          }
        }
      }
      float alpha[4];
      #pragma unroll
      for (int r=0;r<4;r++){
        float mx = fmaxf(fmaxf(S[0][r],S[1][r]), fmaxf(S[2][r],S[3][r]));
        #pragma unroll
        for (int off=8; off>=1; off>>=1) mx = fmaxf(mx, __shfl_xor(mx, off));
        float mnew = fmaxf(m[r], mx);
        alpha[r] = __expf(m[r] - mnew);
        m[r] = mnew;
        l[r] *= alpha[r];
      }
      #pragma unroll
      for (int st=0;st<4;st++)
        #pragma unroll
        for (int r=0;r<4;r++)
          S[st][r] = __expf(S[st][r] - m[r]);
      #pragma unroll
      for (int r=0;r<4;r++){
        float sum = S[0][r]+S[1][r]+S[2][r]+S[3][r];
        #pragma unroll
        for (int off=8; off>=1; off>>=1) sum += __shfl_xor(sum, off);
        l[r] += sum;
      }
      #pragma unroll
      for (int vt=0; vt<8; vt++)
        #pragma unroll
        for (int r=0;r<4;r++) o[vt][r] *= alpha[r];

      #pragma unroll
      for (int st=0;st<4;st++){
        #pragma unroll
        for (int r=0;r<4;r++){
          int qrow = g*4 + r, scol = st*16 + l16;
          unsigned byte = (unsigned)(qrow*128 + scol*2) ^ ((unsigned)(qrow&7)<<4);
          *reinterpret_cast<short*>(PB + byte) = f2bf(S[st][r]);
        }
      }
      bf16x8 pf[2];
      #pragma unroll
      for (int c=0;c<2;c++){
        unsigned byte = (unsigned)(l16*128 + (c*32 + g*8)*2) ^ ((unsigned)(l16&7)<<4);
        pf[c] = *reinterpret_cast<const bf16x8*>(PB + byte);
      }
      __builtin_amdgcn_s_setprio(1);
      #pragma unroll
      for (int vt=0; vt<8; vt++){
        #pragma unroll
        for (int c=0;c<2;c++){
          int vrow = vt*16 + l16;
          int rot = (vrow >> 3) & 7;
          unsigned byte = (unsigned)(vrow*128 + ((c*64 + g*16 + rot*16) & 127));
          bf16x8 vf = *reinterpret_cast<const bf16x8*>(VB + byte);
          o[vt] = __builtin_amdgcn_mfma_f32_16x16x32_bf16(pf[c], vf, o[vt], 0, 0, 0);
        }
      }
      __builtin_amdgcn_s_setprio(0);

      if (more){
        __syncthreads();
        stage_write();
        __syncthreads();
      }
    }

    #pragma unroll
    for (int r=0;r<4;r++){
      float inv = 1.f / l[r];
      int t = t0 + w*16 + g*4 + r;
      #pragma unroll
      for (int vt=0;vt<8;vt++){
        int v = vt*16 + l16;
        attn_out[(size_t)t*16384 + n*128 + v] = f2bf(o[vt][r] * inv);
      }
    }
  }
}

// ---------------------------------------------------------------------------
extern "C" void kernel_launch(void* const* d_in, const int* in_sizes, int n_in,
                              void* d_out, int out_size, void* d_ws, size_t ws_size,
                              hipStream_t stream) {
  const float* x            = (const float*)d_in[0];
  const int*   positions    = (const int*)  d_in[1];
  const float* w_q_down     = (const float*)d_in[2];
  const float* q_norm_scale = (const float*)d_in[3];
  const float* w_q_up       = (const float*)d_in[4];
  const float* w_kv_down    = (const float*)d_in[5];
  const float* kv_norm_scale= (const float*)d_in[6];
  const float* w_kv_up      = (const float*)d_in[7];
  const float* w_o          = (const float*)d_in[8];

  char* p = (char*)d_ws;
  short* xbf   = (short*)p; p += (size_t)1024*7168*2;    // 14.7 MB
  short* wdT   = (short*)p; p += (size_t)2112*7168*2;    // 30.3 MB  [2112][7168]
  short* wquT  = (short*)p; p += (size_t)24576*1536*2;   // 75.5 MB
  short* wkuT  = (short*)p; p += (size_t)32768*512*2;    // 33.6 MB
  short* woT   = (short*)p; p += (size_t)7168*16384*2;   // 234.9 MB
  float* downC = (float*)p; p += (size_t)1024*2112*4;    // 8.7 MB
  short* qAbf  = (short*)p; p += (size_t)1024*1536*2;    // 3.1 MB
  short* q_b   = (short*)p; p += (size_t)1024*24576*2;   // 50.3 MB
  short* cbuf  = (short*)p; p += (size_t)1024*512*2;     // 1.0 MB
  short* krope = (short*)p; p += (size_t)1024*64*2;      // 0.13 MB
  short* kvup  = (short*)p; p += (size_t)1024*32768*2;   // 67 MB
  short* attn_o= (short*)p; p += (size_t)1024*16384*2;   // 33.6 MB

  float* pDown = (float*)q_b;     // 4 planes of 1024x2112 f32 (q_b dead here)
  float* pWo   = (float*)d_ws;    // 2 planes of 1024x7168 f32 (prepass bufs dead)

  hipFuncSetAttribute(reinterpret_cast<const void*>(&gemm256<short,1>),
                      hipFuncAttributeMaxDynamicSharedMemorySize, 131072);
  hipFuncSetAttribute(reinterpret_cast<const void*>(&gemm256<float,2>),
                      hipFuncAttributeMaxDynamicSharedMemorySize, 131072);

  dim3 blk(256);
  // ---- prepass: convert + transpose ----
  conv_f32_bf16<<<2048, blk, 0, stream>>>(x, xbf, 1024*7168/4);
  transpose_f32_bf16<<<dim3(24, 112),  blk, 0, stream>>>(w_q_down,  wdT,                     7168, 1536);
  transpose_f32_bf16<<<dim3(9, 112),   blk, 0, stream>>>(w_kv_down, wdT + (size_t)1536*7168, 7168, 576);
  transpose_f32_bf16<<<dim3(384, 24),  blk, 0, stream>>>(w_q_up,    wquT,                    1536, 24576);
  transpose_f32_bf16<<<dim3(512, 8),   blk, 0, stream>>>(w_kv_up,   wkuT,                    512,  32768);
  transpose_f32_bf16<<<dim3(112, 256), blk, 0, stream>>>(w_o,       woT,                     16384, 7168);

  // ---- fused down-proj (old kernel, split-K=4) + fused post ----
  gemm_bt<float, 4><<<dim3(8, 17, 4), blk, 0, stream>>>(xbf, wdT, (float*)nullptr, pDown, 1024, 2112, 7168);
  reduceN<4><<<1024, blk, 0, stream>>>(pDown, downC, 1024*2112/4, 1024*2112/4);
  mla_post<<<1024, blk, 0, stream>>>(downC, q_norm_scale, kv_norm_scale, positions, qAbf, cbuf, krope);

  // ---- up-projections (gemm256, round-8 config) ----
  gemm256<short, 1><<<dim3(4, 96), dim3(512), 131072, stream>>>(qAbf, wquT, q_b, nullptr, 1024, 24576, 1536);
  mla_rope_q<<<1024, blk, 0, stream>>>(q_b, positions);
  gemm256<short, 1><<<dim3(4, 128), dim3(512), 131072, stream>>>(cbuf, wkuT, kvup, nullptr, 1024, 32768, 512);

  // ---- attention ----
  mla_attn2<<<512, dim3(512), 0, stream>>>(q_b, kvup, krope, attn_o);

  // ---- output projection (gemm256, split-K=2) ----
  gemm256<float, 2><<<dim3(4, 28, 2), dim3(512), 131072, stream>>>(attn_o, woT, (float*)nullptr, pWo, 1024, 7168, 16384);
  reduceN<2><<<2048, blk, 0, stream>>>(pWo, (float*)d_out, 1024*7168/4, 1024*7168/4);
}